// Round 2
// baseline (197.710 us; speedup 1.0000x reference)
//
#include <hip/hip_runtime.h>
#include <cstddef>

#define BSZ 64
#define GG  64
#define LL  100
#define DD  64
#define NG  4   // groups per block

// q layout in ws: q1[64] | q2[64] | q3[64] | bp
__global__ void precompute_kernel(const float* __restrict__ W1,
                                  const float* __restrict__ W2,
                                  const float* __restrict__ W3,
                                  const float* __restrict__ b,
                                  const float* __restrict__ p,
                                  float* __restrict__ q) {
    int d = threadIdx.x;  // 64 threads
    float s1 = 0.f, s2 = 0.f, s3 = 0.f;
    for (int e = 0; e < DD; ++e) {
        float pe = p[e];
        s1 += W1[d * DD + e] * pe;
        s2 += W2[d * DD + e] * pe;
        s3 += W3[d * DD + e] * pe;
    }
    q[d] = s1; q[DD + d] = s2; q[2 * DD + d] = s3;
    float t = b[d] * p[d];
    #pragma unroll
    for (int off = 32; off > 0; off >>= 1) t += __shfl_down(t, off);
    if (d == 0) q[3 * DD] = t;
}

__global__ __launch_bounds__(256) void seq_encoder_kernel(
    const float* __restrict__ seqs, const int* __restrict__ lens,
    const float* __restrict__ q,
    const float* __restrict__ Wq,  const float* __restrict__ Wl0,
    const float* __restrict__ bl0, const float* __restrict__ Wl1,
    const float* __restrict__ bl1, float* __restrict__ out) {
    __shared__ float s_attn[LL];      // emb (partial), then attn
    __shared__ float s_part[4][DD];   // cross-wave reduction scratch
    __shared__ float s_last[DD];
    __shared__ float s_w[NG][DD];     // weighted pooling result per group
    __shared__ float s_h0[NG][2 * DD];
    __shared__ float s_h1[NG][2 * DD];

    const int tid = threadIdx.x;
    const int r = tid >> 6;      // wave id 0..3
    const int d = tid & 63;      // lane = feature dim
    const float q1d = q[d], q2d = q[DD + d], q3d = q[2 * DD + d], bp = q[3 * DD];

    for (int i = 0; i < NG; ++i) {
        const int gi = blockIdx.x * NG + i;
        const float* S = seqs + (size_t)gi * (LL * DD);
        float xr[25];
        float csum = 0.f;
        #pragma unroll
        for (int k = 0; k < 25; ++k) {
            int l = r + 4 * k;
            float x = S[l * DD + d];
            xr[k] = x;
            csum += x;
        }
        // per-row dot with q2 -> emb partial (wave-reduce over 64 lanes)
        #pragma unroll
        for (int k = 0; k < 25; ++k) {
            float t = xr[k] * q2d;
            #pragma unroll
            for (int off = 32; off > 0; off >>= 1) t += __shfl_down(t, off);
            if (d == 0) s_attn[r + 4 * k] = t;
        }
        s_part[r][d] = csum;
        if (r == 3) s_last[d] = xr[24];   // row 99
        __syncthreads();

        if (r == 0) {
            float tot = s_part[0][d] + s_part[1][d] + s_part[2][d] + s_part[3][d];
            float avg = tot / (float)lens[gi];
            float t = s_last[d] * q1d + avg * q3d;
            #pragma unroll
            for (int off = 32; off > 0; off >>= 1) t += __shfl_xor(t, off);
            float c = t + bp;   // all lanes of wave 0 have it
            // softmax over 100 entries
            float e0 = s_attn[d] + c;
            float e1 = (d < LL - 64) ? (s_attn[64 + d] + c) : -1e30f;
            float m = fmaxf(e0, e1);
            #pragma unroll
            for (int off = 32; off > 0; off >>= 1) m = fmaxf(m, __shfl_xor(m, off));
            float x0 = __expf(e0 - m);
            float x1 = (d < LL - 64) ? __expf(e1 - m) : 0.f;
            float s = x0 + x1;
            #pragma unroll
            for (int off = 32; off > 0; off >>= 1) s += __shfl_xor(s, off);
            float inv = 1.f / s;
            s_attn[d] = x0 * inv;
            if (d < LL - 64) s_attn[64 + d] = x1 * inv;
        }
        __syncthreads();

        // weighted pooling, reusing register-resident tile
        float wp = 0.f;
        #pragma unroll
        for (int k = 0; k < 25; ++k) wp += s_attn[r + 4 * k] * xr[k];
        s_part[r][d] = wp;
        __syncthreads();
        if (r == 0)
            s_w[i][d] = s_part[0][d] + s_part[1][d] + s_part[2][d] + s_part[3][d];
        __syncthreads();
    }

    // ---- MLP phase: 128 threads per half, 2 groups per half ----
    const int jt = tid & 127;
    const int i0 = (tid >> 7) * 2;   // groups {i0, i0+1}
    float h0a = 0.f, h0b = 0.f;
    for (int dd2 = 0; dd2 < DD; ++dd2) {
        float w = Wq[dd2 * (2 * DD) + jt];
        h0a += s_w[i0][dd2] * w;
        h0b += s_w[i0 + 1][dd2] * w;
    }
    s_h0[i0][jt] = h0a;
    s_h0[i0 + 1][jt] = h0b;
    __syncthreads();

    float a1 = bl0[jt], b1 = bl0[jt];
    for (int k = 0; k < 2 * DD; ++k) {
        float w = Wl0[k * (2 * DD) + jt];
        a1 += s_h0[i0][k] * w;
        b1 += s_h0[i0 + 1][k] * w;
    }
    a1 = fmaxf(a1, 0.f); b1 = fmaxf(b1, 0.f);
    s_h1[i0][jt] = a1;
    s_h1[i0 + 1][jt] = b1;
    __syncthreads();

    float a2 = bl1[jt], b2 = bl1[jt];
    for (int k = 0; k < 2 * DD; ++k) {
        float w = Wl1[k * (2 * DD) + jt];
        a2 += s_h1[i0][k] * w;
        b2 += s_h1[i0 + 1][k] * w;
    }
    a2 = fmaxf(a2, 0.f); b2 = fmaxf(b2, 0.f);

    const size_t gbase = (size_t)blockIdx.x * NG;
    out[(gbase + i0) * (2 * DD) + jt]     = h0a + a2;
    out[(gbase + i0 + 1) * (2 * DD) + jt] = h0b + b2;
}

extern "C" void kernel_launch(void* const* d_in, const int* in_sizes, int n_in,
                              void* d_out, int out_size, void* d_ws, size_t ws_size,
                              hipStream_t stream) {
    const float* seqs = (const float*)d_in[0];
    const int*   lens = (const int*)d_in[1];
    const float* W1   = (const float*)d_in[2];
    const float* W2   = (const float*)d_in[3];
    const float* W3   = (const float*)d_in[4];
    const float* b    = (const float*)d_in[5];
    const float* p    = (const float*)d_in[6];
    const float* Wq   = (const float*)d_in[7];
    const float* Wl0  = (const float*)d_in[8];
    const float* bl0  = (const float*)d_in[9];
    const float* Wl1  = (const float*)d_in[10];
    const float* bl1  = (const float*)d_in[11];
    float* out = (float*)d_out;
    float* q   = (float*)d_ws;   // 193 floats

    precompute_kernel<<<1, 64, 0, stream>>>(W1, W2, W3, b, p, q);
    seq_encoder_kernel<<<(BSZ * GG) / NG, 256, 0, stream>>>(
        seqs, lens, q, Wq, Wl0, bl0, Wl1, bl1, out);
}